// Round 7
// baseline (119.650 us; speedup 1.0000x reference)
//
#include <hip/hip_runtime.h>

#define HH 512
#define WD 512
#define HP 514
#define BN 8
#define CN 3

#define TH 16
#define TW 64

// Single LDS tile: channel-packed float4. .xyz = img_p ch0..2 (immutable after
// phase 1). .w is a multiplexed scratch plane:
//   phase 1: 0
//   phase 2: img_r[i,j] stored at the slot of img_p[i+1,j+1]  (+1,+1 shift)
//   phase 3b: w_mod[i,j] stored at the slot of img_p[i+1,j+1] (same shift)
// The +1,+1 shift makes every consumer's 9-tap b128 read deliver the img_p
// value AND its paired img_r / w_mod value in one load.
// Race safety: .w is only ever read in a phase after a __syncthreads from the
// phase that wrote it; concurrent b128 reads during a .w write only use .xyz.
#define SP_ROWS (TH + 6)          // 22  img_p rows [h0-2, h0+20)
#define SP_COLS (TW + 6)          // 70  img_p cols [w0-2, w0+68)
#define SR_ROWS (TH + 4)          // 20  img_r rows [h0-2, h0+18)
#define SR_COLS (TW + 4)          // 68
#define WM_ROWS (TH + 2)          // 18  w_mod rows [h0-1, h0+17)
#define WM_COLS (TW + 2)          // 66
#define WM_ITERS ((WM_ROWS * WM_COLS + 255) / 256)  // 5

// Robust per-batch flag read: contract says int32, hedge for bool bytes.
__device__ __forceinline__ int load_flag(const int* __restrict__ p, int b) {
    bool all01 = true;
#pragma unroll
    for (int i = 0; i < BN; ++i) {
        int v = p[i];
        all01 = all01 && (v == 0 || v == 1);
    }
    if (all01) return p[b];
    const unsigned char* pb = (const unsigned char*)p;
    return pb[b] != 0;
}

__device__ __forceinline__ float fast_rcp(float x) {
    return __builtin_amdgcn_rcpf(x);
}

__global__ __launch_bounds__(256) void fused(const float* __restrict__ img,
                                             const float* __restrict__ noise,
                                             const int* __restrict__ ids_sel,
                                             const int* __restrict__ ids_dil,
                                             int* __restrict__ out) {
    int b = blockIdx.z;
    int h0 = blockIdx.y * TH, w0 = blockIdx.x * TW;
    int t = threadIdx.x;
    int tx = t & 63, ty = t >> 6;

    if (!load_flag(ids_sel, b)) {  // uniform per block: plain uint8 copy
#pragma unroll
        for (int c = 0; c < CN; ++c) {
            const float* im = img + (size_t)(b * CN + c) * HH * WD;
            int* op = out + (size_t)(b * CN + c) * HH * WD;
#pragma unroll
            for (int rr = 0; rr < 4; ++rr) {
                int ly = ty * 4 + rr;
                op[(h0 + ly) * WD + w0 + tx] = ((int)im[(h0 + ly) * WD + w0 + tx]) & 255;
            }
        }
        return;
    }
    bool dil = load_flag(ids_dil, b) != 0;

    __shared__ float4 sp4[SP_ROWS * SP_COLS];  // 24,640 B — only LDS array

    // Phase 1: stage img_p (3ch packed) rows [h0-2,h0+20), cols [w0-2,w0+68).
    // Index-clamped; clamped entries feed only out-of-image pixels (forced 0).
    {
        const float* nz = noise + (size_t)b * CN * HP * HP;
        const float* im = img + (size_t)b * CN * HH * WD;
        for (int idx = t; idx < SP_ROWS * SP_COLS; idx += 256) {
            int r = idx / SP_COLS, cc = idx - r * SP_COLS;
            int ip = h0 - 2 + r, jp = w0 - 2 + cc;
            ip = ip < 0 ? 0 : (ip > HP - 1 ? HP - 1 : ip);
            jp = jp < 0 ? 0 : (jp > HP - 1 ? HP - 1 : jp);
            bool in = (ip >= 1 && ip <= HH && jp >= 1 && jp <= WD);
            int no = ip * HP + jp;
            int io = (ip - 1) * WD + (jp - 1);
            float4 v;
            v.x = nz[no] + (in ? im[io] : 0.f);
            v.y = nz[HP * HP + no] + (in ? im[HH * WD + io] : 0.f);
            v.z = nz[2 * HP * HP + no] + (in ? im[2 * HH * WD + io] : 0.f);
            v.w = 0.f;
            sp4[idx] = v;
        }
    }
    __syncthreads();

    // Phase 2: img_r for pixel rows [h0-2,h0+18), cols [w0-2,w0+66), written
    // into sp4[.w] with the +1,+1 shift. min_c exp(-t) == exp(-max_c t).
    for (int idx = t; idx < SR_ROWS * SR_COLS; idx += 256) {
        int r = idx / SR_COLS, cc = idx - r * SR_COLS;
        int h = h0 - 2 + r, w = w0 - 2 + cc;
        float val = 0.f;
        if (h >= 0 && h < HH && w >= 0 && w < WD) {
            float4 tp[9];
#pragma unroll
            for (int k = 0; k < 9; ++k)
                tp[k] = sp4[(r + k / 3) * SP_COLS + cc + k % 3];
            float sx = 0.f, sy = 0.f, sz = 0.f;
#pragma unroll
            for (int k = 0; k < 9; ++k) { sx += tp[k].x; sy += tp[k].y; sz += tp[k].z; }
            float mx = sx * (1.f / 9.f), my = sy * (1.f / 9.f), mz = sz * (1.f / 9.f);
            float sdx = 0.f, sdy = 0.f, sdz = 0.f;
#pragma unroll
            for (int k = 0; k < 9; ++k) {
                float dx = tp[k].x - mx, dy = tp[k].y - my, dz = tp[k].z - mz;
                sdx += dx * dx; sdy += dy * dy; sdz += dz * dz;
            }
            float ivx = 4.f * fast_rcp(sdx);  // 1/(2*var), var = sd/8 (ddof=1)
            float ivy = 4.f * fast_rcp(sdy);
            float ivz = 4.f * fast_rcp(sdz);
            float num = 0.f, den = 0.f;
#pragma unroll
            for (int k = 0; k < 9; ++k) {
                float dx = tp[k].x - mx, dy = tp[k].y - my, dz = tp[k].z - mz;
                float txx = dx * dx * ivx, tyy = dy * dy * ivy, tzz = dz * dz * ivz;
                float m = fmaxf(txx, fmaxf(tyy, tzz));
                float wk = __expf(-m);
                num += (tp[k].x + tp[k].y + tp[k].z) * wk;
                den += wk;
            }
            val = num * fast_rcp(den);
        }
        sp4[(r + 1) * SP_COLS + cc + 1].w = val;  // ds_write_b32 at +12
    }
    __syncthreads();

    // Phase 3a: w_mod for pixel rows [h0-1,h0+17), cols [w0-1,w0+65), into
    // registers. Each 9-tap b128 read gives img_p (.xyz) + img_r tap (.w).
    float wmv_reg[WM_ITERS];
#pragma unroll
    for (int it = 0; it < WM_ITERS; ++it) {
        int idx = t + it * 256;
        float wmv = 0.f;
        if (idx < WM_ROWS * WM_COLS) {
            int r = idx / WM_COLS, cc = idx - r * WM_COLS;
            int h = h0 - 1 + r, w = w0 - 1 + cc;
            if (h >= 0 && h < HH && w >= 0 && w < WD) {
                float4 tp[9];
#pragma unroll
                for (int k = 0; k < 9; ++k)
                    tp[k] = sp4[(r + 1 + k / 3) * SP_COLS + cc + 1 + k % 3];
                int amin = 0, amax = 0;
                float vmin = tp[0].w, vmax = tp[0].w;
#pragma unroll
                for (int k = 1; k < 9; ++k) {
                    if (tp[k].w < vmin) { vmin = tp[k].w; amin = k; }  // first occurrence
                    if (tp[k].w > vmax) { vmax = tp[k].w; amax = k; }
                }
                int ksel = dil ? amax : amin;
                float sx = 0.f, sy = 0.f, sz = 0.f;
#pragma unroll
                for (int k = 0; k < 9; ++k) { sx += tp[k].x; sy += tp[k].y; sz += tp[k].z; }
                float mx = sx * (1.f / 9.f), my = sy * (1.f / 9.f), mz = sz * (1.f / 9.f);
                float sdx = 0.f, sdy = 0.f, sdz = 0.f;
#pragma unroll
                for (int k = 0; k < 9; ++k) {
                    float dx = tp[k].x - mx, dy = tp[k].y - my, dz = tp[k].z - mz;
                    sdx += dx * dx; sdy += dy * dy; sdz += dz * dz;
                }
                // selected tap via ONE dynamic LDS read (never a dynamic
                // register-array index — scratch-spill trap, see R5)
                float4 s = sp4[(r + 1 + ksel / 3) * SP_COLS + cc + 1 + ksel % 3];
                float dx = s.x - mx, dy = s.y - my, dz = s.z - mz;
                float txx = dx * dx * (4.f * fast_rcp(sdx));
                float tyy = dy * dy * (4.f * fast_rcp(sdy));
                float tzz = dz * dz * (4.f * fast_rcp(sdz));
                wmv = __expf(-fmaxf(txx, fmaxf(tyy, tzz)));
            }
        }
        wmv_reg[it] = wmv;
    }
    __syncthreads();  // all img_r reads done before .w is overwritten

    // Phase 3b: publish w_mod into sp4[.w] (+1,+1 shift; overwrites dead img_r)
#pragma unroll
    for (int it = 0; it < WM_ITERS; ++it) {
        int idx = t + it * 256;
        if (idx < WM_ROWS * WM_COLS) {
            int r = idx / WM_COLS, cc = idx - r * WM_COLS;
            sp4[(r + 2) * SP_COLS + cc + 2].w = wmv_reg[it];
        }
    }
    __syncthreads();

    // Phase 4: final weighted average. One b128 tap = pixel (.xyz) + its
    // paired weight (.w), thanks to the +1,+1 shift.
#pragma unroll
    for (int rr = 0; rr < 4; ++rr) {
        int ly = ty * 4 + rr;
        float den = 0.f, nx = 0.f, ny = 0.f, nz2 = 0.f;
#pragma unroll
        for (int k = 0; k < 9; ++k) {
            float4 tp = sp4[(ly + 2 + k / 3) * SP_COLS + tx + 2 + k % 3];
            den += tp.w;
            nx += tp.x * tp.w;
            ny += tp.y * tp.w;
            nz2 += tp.z * tp.w;
        }
        float rden = 1.f / den;
        size_t o = ((size_t)b * CN * HH + h0 + ly) * WD + w0 + tx;
        out[o] = ((int)(nx * rden)) & 255;
        out[o + (size_t)HH * WD] = ((int)(ny * rden)) & 255;
        out[o + 2 * (size_t)HH * WD] = ((int)(nz2 * rden)) & 255;
    }
}

extern "C" void kernel_launch(void* const* d_in, const int* in_sizes, int n_in,
                              void* d_out, int out_size, void* d_ws, size_t ws_size,
                              hipStream_t stream) {
    const float* img   = (const float*)d_in[0];
    const float* noise = (const float*)d_in[1];
    const int* ids_sel = (const int*)d_in[2];
    const int* ids_dil = (const int*)d_in[3];
    int* out = (int*)d_out;

    dim3 grid(WD / TW, HH / TH, BN);  // 8 x 32 x 8 = 2048 blocks
    fused<<<grid, 256, 0, stream>>>(img, noise, ids_sel, ids_dil, out);
}

// Round 8
// 113.700 us; speedup vs baseline: 1.0523x; 1.0523x over previous
//
#include <hip/hip_runtime.h>

#define HH 512
#define WD 512
#define HP 514
#define BN 8
#define CN 3

#define TH 16
#define TW 32

// LDS tiles. sp4 is channel-packed float4 (.xyz = ch0..2, .w dead) so one tap
// = one 16B-aligned ds_read_b128. sr/swm scalar with odd pitch (conflict-free).
// Tile 32x16 -> 4096 blocks (16/CU): occupancy is grid/balance-limited, not
// LDS-limited (R7 evidence), so more+smaller blocks win despite 1.41x halo.
#define SP_ROWS (TH + 6)          // 22  img_p rows [h0-2, h0+20)
#define SP_COLS (TW + 6)          // 38  img_p cols [w0-2, w0+38)
#define SR_ROWS (TH + 4)          // 20  img_r rows [h0-2, h0+18)
#define SR_COLS (TW + 4)          // 36
#define SR_PITCH (SR_COLS + 1)    // 37
#define WM_ROWS (TH + 2)          // 18  w_mod rows [h0-1, h0+17)
#define WM_COLS (TW + 2)          // 34
#define WM_PITCH (WM_COLS + 1)    // 35

// Robust per-batch flag read: contract says int32, hedge for bool bytes.
__device__ __forceinline__ int load_flag(const int* __restrict__ p, int b) {
    bool all01 = true;
#pragma unroll
    for (int i = 0; i < BN; ++i) {
        int v = p[i];
        all01 = all01 && (v == 0 || v == 1);
    }
    if (all01) return p[b];
    const unsigned char* pb = (const unsigned char*)p;
    return pb[b] != 0;
}

__device__ __forceinline__ float fast_rcp(float x) {
    return __builtin_amdgcn_rcpf(x);
}

__global__ __launch_bounds__(256) void fused(const float* __restrict__ img,
                                             const float* __restrict__ noise,
                                             const int* __restrict__ ids_sel,
                                             const int* __restrict__ ids_dil,
                                             int* __restrict__ out) {
    int b = blockIdx.z;
    int h0 = blockIdx.y * TH, w0 = blockIdx.x * TW;
    int t = threadIdx.x;

    if (!load_flag(ids_sel, b)) {  // uniform per block: plain uint8 copy
#pragma unroll
        for (int c = 0; c < CN; ++c) {
            const float* im = img + (size_t)(b * CN + c) * HH * WD;
            int* op = out + (size_t)(b * CN + c) * HH * WD;
#pragma unroll
            for (int rr = 0; rr < (TH * TW) / 256; ++rr) {
                int idx = rr * 256 + t;
                int r = idx / TW, cc = idx - r * TW;
                op[(h0 + r) * WD + w0 + cc] = ((int)im[(h0 + r) * WD + w0 + cc]) & 255;
            }
        }
        return;
    }
    bool dil = load_flag(ids_dil, b) != 0;

    __shared__ float4 sp4[SP_ROWS * SP_COLS];  // 13,376 B
    __shared__ float sr[SR_ROWS * SR_PITCH];   //  2,960 B
    __shared__ float swm[WM_ROWS * WM_PITCH];  //  2,520 B

    // Phase 1: stage img_p (3ch packed) rows [h0-2,h0+20), cols [w0-2,w0+36).
    // Index-clamped; clamped entries feed only out-of-image pixels (forced 0).
    {
        const float* nz = noise + (size_t)b * CN * HP * HP;
        const float* im = img + (size_t)b * CN * HH * WD;
        for (int idx = t; idx < SP_ROWS * SP_COLS; idx += 256) {
            int r = idx / SP_COLS, cc = idx - r * SP_COLS;
            int ip = h0 - 2 + r, jp = w0 - 2 + cc;
            ip = ip < 0 ? 0 : (ip > HP - 1 ? HP - 1 : ip);
            jp = jp < 0 ? 0 : (jp > HP - 1 ? HP - 1 : jp);
            bool in = (ip >= 1 && ip <= HH && jp >= 1 && jp <= WD);
            int no = ip * HP + jp;
            int io = (ip - 1) * WD + (jp - 1);
            float4 v;
            v.x = nz[no] + (in ? im[io] : 0.f);
            v.y = nz[HP * HP + no] + (in ? im[HH * WD + io] : 0.f);
            v.z = nz[2 * HP * HP + no] + (in ? im[2 * HH * WD + io] : 0.f);
            v.w = 0.f;
            sp4[idx] = v;
        }
    }
    __syncthreads();

    // Phase 2: img_r for pixel rows [h0-2,h0+18), cols [w0-2,w0+34).
    // min_c exp(-t_c) == exp(-max_c t_c): 9 exps/px. tp[] static-indexed only.
    for (int idx = t; idx < SR_ROWS * SR_COLS; idx += 256) {
        int r = idx / SR_COLS, cc = idx - r * SR_COLS;
        int h = h0 - 2 + r, w = w0 - 2 + cc;
        float val = 0.f;
        if (h >= 0 && h < HH && w >= 0 && w < WD) {
            float4 tp[9];
#pragma unroll
            for (int k = 0; k < 9; ++k)
                tp[k] = sp4[(r + k / 3) * SP_COLS + cc + k % 3];
            float sx = 0.f, sy = 0.f, sz = 0.f;
#pragma unroll
            for (int k = 0; k < 9; ++k) { sx += tp[k].x; sy += tp[k].y; sz += tp[k].z; }
            float mx = sx * (1.f / 9.f), my = sy * (1.f / 9.f), mz = sz * (1.f / 9.f);
            float sdx = 0.f, sdy = 0.f, sdz = 0.f;
#pragma unroll
            for (int k = 0; k < 9; ++k) {
                float dx = tp[k].x - mx, dy = tp[k].y - my, dz = tp[k].z - mz;
                sdx += dx * dx; sdy += dy * dy; sdz += dz * dz;
            }
            float ivx = 4.f * fast_rcp(sdx);  // 1/(2*var), var = sd/8 (ddof=1)
            float ivy = 4.f * fast_rcp(sdy);
            float ivz = 4.f * fast_rcp(sdz);
            float num = 0.f, den = 0.f;
#pragma unroll
            for (int k = 0; k < 9; ++k) {
                float dx = tp[k].x - mx, dy = tp[k].y - my, dz = tp[k].z - mz;
                float txx = dx * dx * ivx, tyy = dy * dy * ivy, tzz = dz * dz * ivz;
                float m = fmaxf(txx, fmaxf(tyy, tzz));
                float wk = __expf(-m);
                num += (tp[k].x + tp[k].y + tp[k].z) * wk;
                den += wk;
            }
            val = num * fast_rcp(den);
        }
        sr[r * SR_PITCH + cc] = val;
    }
    __syncthreads();

    // Phase 3: w_mod for pixel rows [h0-1,h0+17), cols [w0-1,w0+33).
    // Selected tap via ONE dynamic LDS read (never a dynamically-indexed
    // register array — scratch-spill trap, see R5).
    for (int idx = t; idx < WM_ROWS * WM_COLS; idx += 256) {
        int r = idx / WM_COLS, cc = idx - r * WM_COLS;
        int h = h0 - 1 + r, w = w0 - 1 + cc;
        float wmv = 0.f;
        if (h >= 0 && h < HH && w >= 0 && w < WD) {
            float rv[9];
#pragma unroll
            for (int k = 0; k < 9; ++k)
                rv[k] = sr[(r + k / 3) * SR_PITCH + cc + k % 3];
            int amin = 0, amax = 0;
            float vmin = rv[0], vmax = rv[0];
#pragma unroll
            for (int k = 1; k < 9; ++k) {
                if (rv[k] < vmin) { vmin = rv[k]; amin = k; }  // first occurrence
                if (rv[k] > vmax) { vmax = rv[k]; amax = k; }
            }
            int ksel = dil ? amax : amin;

            float4 tp[9];
#pragma unroll
            for (int k = 0; k < 9; ++k)
                tp[k] = sp4[(r + 1 + k / 3) * SP_COLS + cc + 1 + k % 3];
            float sx = 0.f, sy = 0.f, sz = 0.f;
#pragma unroll
            for (int k = 0; k < 9; ++k) { sx += tp[k].x; sy += tp[k].y; sz += tp[k].z; }
            float mx = sx * (1.f / 9.f), my = sy * (1.f / 9.f), mz = sz * (1.f / 9.f);
            float sdx = 0.f, sdy = 0.f, sdz = 0.f;
#pragma unroll
            for (int k = 0; k < 9; ++k) {
                float dx = tp[k].x - mx, dy = tp[k].y - my, dz = tp[k].z - mz;
                sdx += dx * dx; sdy += dy * dy; sdz += dz * dz;
            }
            float4 s = sp4[(r + 1 + ksel / 3) * SP_COLS + cc + 1 + ksel % 3];
            float dx = s.x - mx, dy = s.y - my, dz = s.z - mz;
            float txx = dx * dx * (4.f * fast_rcp(sdx));
            float tyy = dy * dy * (4.f * fast_rcp(sdy));
            float tzz = dz * dz * (4.f * fast_rcp(sdz));
            wmv = __expf(-fmaxf(txx, fmaxf(tyy, tzz)));
        }
        swm[r * WM_PITCH + cc] = wmv;
    }
    __syncthreads();

    // Phase 4: final weighted average per output pixel, 3 channels at once.
#pragma unroll
    for (int rr = 0; rr < (TH * TW) / 256; ++rr) {
        int idx = rr * 256 + t;
        int ly = idx / TW, lx = idx - ly * TW;
        float wk[9], den = 0.f;
#pragma unroll
        for (int k = 0; k < 9; ++k) {
            wk[k] = swm[(ly + k / 3) * WM_PITCH + lx + k % 3];
            den += wk[k];
        }
        float rden = 1.f / den;
        float nx = 0.f, ny = 0.f, nz2 = 0.f;
#pragma unroll
        for (int k = 0; k < 9; ++k) {
            float4 tp = sp4[(ly + 2 + k / 3) * SP_COLS + lx + 2 + k % 3];
            nx += tp.x * wk[k];
            ny += tp.y * wk[k];
            nz2 += tp.z * wk[k];
        }
        size_t o = ((size_t)b * CN * HH + h0 + ly) * WD + w0 + lx;
        out[o] = ((int)(nx * rden)) & 255;
        out[o + (size_t)HH * WD] = ((int)(ny * rden)) & 255;
        out[o + 2 * (size_t)HH * WD] = ((int)(nz2 * rden)) & 255;
    }
}

extern "C" void kernel_launch(void* const* d_in, const int* in_sizes, int n_in,
                              void* d_out, int out_size, void* d_ws, size_t ws_size,
                              hipStream_t stream) {
    const float* img   = (const float*)d_in[0];
    const float* noise = (const float*)d_in[1];
    const int* ids_sel = (const int*)d_in[2];
    const int* ids_dil = (const int*)d_in[3];
    int* out = (int*)d_out;

    dim3 grid(WD / TW, HH / TH, BN);  // 16 x 32 x 8 = 4096 blocks
    fused<<<grid, 256, 0, stream>>>(img, noise, ids_sel, ids_dil, out);
}

// Round 9
// 110.692 us; speedup vs baseline: 1.0809x; 1.0272x over previous
//
#include <hip/hip_runtime.h>
#include <hip/hip_fp16.h>

#define HH 512
#define WD 512
#define HP 514
#define BN 8
#define CN 3

#define TH 16
#define TW 32

// LDS tiles. sp4 is channel-packed float4 (.xyz = ch0..2) so one tap = one
// 16B-aligned ds_read_b128. sr/swm scalar with odd pitch (conflict-free).
// w9: per-WM-pixel cache of the 9 Gaussian weights computed in phase 2,
// stored fp16 (20B/px, 5-dword stride -> 2-way bank aliasing = free), so
// phase 3 never recomputes window stats (R8's phase 3 redid ~110 VALU + exp
// per pixel that phase 2 had already done).
#define SP_ROWS (TH + 6)          // 22  img_p rows [h0-2, h0+20)
#define SP_COLS (TW + 6)          // 38
#define SR_ROWS (TH + 4)          // 20  img_r rows [h0-2, h0+18)
#define SR_COLS (TW + 4)          // 36
#define SR_PITCH (SR_COLS + 1)    // 37
#define WM_ROWS (TH + 2)          // 18  w_mod rows [h0-1, h0+17)
#define WM_COLS (TW + 2)          // 34
#define WM_PITCH (WM_COLS + 1)    // 35
#define W9_STRIDE 10              // halves per pixel (9 used, 1 pad -> 20 B)

// Robust per-batch flag read: contract says int32, hedge for bool bytes.
__device__ __forceinline__ int load_flag(const int* __restrict__ p, int b) {
    bool all01 = true;
#pragma unroll
    for (int i = 0; i < BN; ++i) {
        int v = p[i];
        all01 = all01 && (v == 0 || v == 1);
    }
    if (all01) return p[b];
    const unsigned char* pb = (const unsigned char*)p;
    return pb[b] != 0;
}

__device__ __forceinline__ float fast_rcp(float x) {
    return __builtin_amdgcn_rcpf(x);
}

__global__ __launch_bounds__(256) void fused(const float* __restrict__ img,
                                             const float* __restrict__ noise,
                                             const int* __restrict__ ids_sel,
                                             const int* __restrict__ ids_dil,
                                             int* __restrict__ out) {
    int b = blockIdx.z;
    int h0 = blockIdx.y * TH, w0 = blockIdx.x * TW;
    int t = threadIdx.x;

    if (!load_flag(ids_sel, b)) {  // uniform per block: plain uint8 copy
#pragma unroll
        for (int c = 0; c < CN; ++c) {
            const float* im = img + (size_t)(b * CN + c) * HH * WD;
            int* op = out + (size_t)(b * CN + c) * HH * WD;
#pragma unroll
            for (int rr = 0; rr < (TH * TW) / 256; ++rr) {
                int idx = rr * 256 + t;
                int r = idx / TW, cc = idx - r * TW;
                op[(h0 + r) * WD + w0 + cc] = ((int)im[(h0 + r) * WD + w0 + cc]) & 255;
            }
        }
        return;
    }
    bool dil = load_flag(ids_dil, b) != 0;

    __shared__ float4 sp4[SP_ROWS * SP_COLS];               // 13,376 B
    __shared__ float sr[SR_ROWS * SR_PITCH];                //  2,960 B
    __shared__ float swm[WM_ROWS * WM_PITCH];               //  2,520 B
    __shared__ __align__(4) __half w9[WM_ROWS * WM_COLS * W9_STRIDE];  // 12,240 B

    // Phase 1: stage img_p (3ch packed) rows [h0-2,h0+20), cols [w0-2,w0+36).
    // Index-clamped; clamped entries feed only out-of-image pixels (forced 0).
    {
        const float* nz = noise + (size_t)b * CN * HP * HP;
        const float* im = img + (size_t)b * CN * HH * WD;
        for (int idx = t; idx < SP_ROWS * SP_COLS; idx += 256) {
            int r = idx / SP_COLS, cc = idx - r * SP_COLS;
            int ip = h0 - 2 + r, jp = w0 - 2 + cc;
            ip = ip < 0 ? 0 : (ip > HP - 1 ? HP - 1 : ip);
            jp = jp < 0 ? 0 : (jp > HP - 1 ? HP - 1 : jp);
            bool in = (ip >= 1 && ip <= HH && jp >= 1 && jp <= WD);
            int no = ip * HP + jp;
            int io = (ip - 1) * WD + (jp - 1);
            float4 v;
            v.x = nz[no] + (in ? im[io] : 0.f);
            v.y = nz[HP * HP + no] + (in ? im[HH * WD + io] : 0.f);
            v.z = nz[2 * HP * HP + no] + (in ? im[2 * HH * WD + io] : 0.f);
            v.w = 0.f;
            sp4[idx] = v;
        }
    }
    __syncthreads();

    // Phase 2: img_r for pixel rows [h0-2,h0+18), cols [w0-2,w0+34), AND the
    // 9 per-pixel weights cached to w9 (fp16) for the WM sub-rect.
    // min_c exp(-t_c) == exp(-max_c t_c): 9 exps/px. tp[] static-indexed only.
    for (int idx = t; idx < SR_ROWS * SR_COLS; idx += 256) {
        int r = idx / SR_COLS, cc = idx - r * SR_COLS;
        int h = h0 - 2 + r, w = w0 - 2 + cc;
        float val = 0.f;
        if (h >= 0 && h < HH && w >= 0 && w < WD) {
            float4 tp[9];
#pragma unroll
            for (int k = 0; k < 9; ++k)
                tp[k] = sp4[(r + k / 3) * SP_COLS + cc + k % 3];
            float sx = 0.f, sy = 0.f, sz = 0.f;
#pragma unroll
            for (int k = 0; k < 9; ++k) { sx += tp[k].x; sy += tp[k].y; sz += tp[k].z; }
            float mx = sx * (1.f / 9.f), my = sy * (1.f / 9.f), mz = sz * (1.f / 9.f);
            float sdx = 0.f, sdy = 0.f, sdz = 0.f;
#pragma unroll
            for (int k = 0; k < 9; ++k) {
                float dx = tp[k].x - mx, dy = tp[k].y - my, dz = tp[k].z - mz;
                sdx += dx * dx; sdy += dy * dy; sdz += dz * dz;
            }
            float ivx = 4.f * fast_rcp(sdx);  // 1/(2*var), var = sd/8 (ddof=1)
            float ivy = 4.f * fast_rcp(sdy);
            float ivz = 4.f * fast_rcp(sdz);
            float wk[9];
            float num = 0.f, den = 0.f;
#pragma unroll
            for (int k = 0; k < 9; ++k) {
                float dx = tp[k].x - mx, dy = tp[k].y - my, dz = tp[k].z - mz;
                float txx = dx * dx * ivx, tyy = dy * dy * ivy, tzz = dz * dz * ivz;
                float m = fmaxf(txx, fmaxf(tyy, tzz));
                wk[k] = __expf(-m);
                num += (tp[k].x + tp[k].y + tp[k].z) * wk[k];
                den += wk[k];
            }
            val = num * fast_rcp(den);
            // cache the 9 weights (fp16, packed dword writes) for phase 3
            if (r >= 1 && r < SR_ROWS - 1 && cc >= 1 && cc < SR_COLS - 1) {
                int pix = (r - 1) * WM_COLS + (cc - 1);
                unsigned int* wp = (unsigned int*)&w9[pix * W9_STRIDE];
#pragma unroll
                for (int k = 0; k < 4; ++k) {
                    __half2 h2 = __floats2half2_rn(wk[2 * k], wk[2 * k + 1]);
                    wp[k] = *(unsigned int*)&h2;
                }
                w9[pix * W9_STRIDE + 8] = __float2half_rn(wk[8]);
            }
        }
        sr[r * SR_PITCH + cc] = val;
    }
    __syncthreads();

    // Phase 3: w_mod for pixel rows [h0-1,h0+17), cols [w0-1,w0+33):
    // argmin/argmax over the img_r window, then ONE dynamic LDS u16 read of
    // the cached weight (never a dynamically-indexed register array — R5).
    for (int idx = t; idx < WM_ROWS * WM_COLS; idx += 256) {
        int r = idx / WM_COLS, cc = idx - r * WM_COLS;
        int h = h0 - 1 + r, w = w0 - 1 + cc;
        float wmv = 0.f;
        if (h >= 0 && h < HH && w >= 0 && w < WD) {
            float rv[9];
#pragma unroll
            for (int k = 0; k < 9; ++k)
                rv[k] = sr[(r + k / 3) * SR_PITCH + cc + k % 3];
            int amin = 0, amax = 0;
            float vmin = rv[0], vmax = rv[0];
#pragma unroll
            for (int k = 1; k < 9; ++k) {
                if (rv[k] < vmin) { vmin = rv[k]; amin = k; }  // first occurrence
                if (rv[k] > vmax) { vmax = rv[k]; amax = k; }
            }
            int ksel = dil ? amax : amin;
            wmv = __half2float(w9[idx * W9_STRIDE + ksel]);
        }
        swm[r * WM_PITCH + cc] = wmv;
    }
    __syncthreads();

    // Phase 4: final weighted average per output pixel, 3 channels at once.
#pragma unroll
    for (int rr = 0; rr < (TH * TW) / 256; ++rr) {
        int idx = rr * 256 + t;
        int ly = idx / TW, lx = idx - ly * TW;
        float wk[9], den = 0.f;
#pragma unroll
        for (int k = 0; k < 9; ++k) {
            wk[k] = swm[(ly + k / 3) * WM_PITCH + lx + k % 3];
            den += wk[k];
        }
        float rden = 1.f / den;
        float nx = 0.f, ny = 0.f, nz2 = 0.f;
#pragma unroll
        for (int k = 0; k < 9; ++k) {
            float4 tp = sp4[(ly + 2 + k / 3) * SP_COLS + lx + 2 + k % 3];
            nx += tp.x * wk[k];
            ny += tp.y * wk[k];
            nz2 += tp.z * wk[k];
        }
        size_t o = ((size_t)b * CN * HH + h0 + ly) * WD + w0 + lx;
        out[o] = ((int)(nx * rden)) & 255;
        out[o + (size_t)HH * WD] = ((int)(ny * rden)) & 255;
        out[o + 2 * (size_t)HH * WD] = ((int)(nz2 * rden)) & 255;
    }
}

extern "C" void kernel_launch(void* const* d_in, const int* in_sizes, int n_in,
                              void* d_out, int out_size, void* d_ws, size_t ws_size,
                              hipStream_t stream) {
    const float* img   = (const float*)d_in[0];
    const float* noise = (const float*)d_in[1];
    const int* ids_sel = (const int*)d_in[2];
    const int* ids_dil = (const int*)d_in[3];
    int* out = (int*)d_out;

    dim3 grid(WD / TW, HH / TH, BN);  // 16 x 32 x 8 = 4096 blocks
    fused<<<grid, 256, 0, stream>>>(img, noise, ids_sel, ids_dil, out);
}